// Round 7
// baseline (2128.693 us; speedup 1.0000x reference)
//
#include <hip/hip_runtime.h>

// BERT classifier fwd, MI355X. Round 7: 256^2 counted-vmcnt pipelined GEMM
// (gemm3_k: raw s_barrier, vmcnt(8), LDS XOR-swizzle, setprio) replaces the
// m97-structure gemm2_k everywhere. Attn/LN/embed/prologue unchanged (proven).

#define E_DIM 768
#define F_DIM 3072
#define L_NUM 4
#define S_LEN 512
#define NTOK  (S_LEN * 32)   // 16384
#define QKVN  (3 * E_DIM)    // 2304

typedef float f32x4 __attribute__((ext_vector_type(4)));
typedef unsigned int u32x4 __attribute__((ext_vector_type(4)));
typedef unsigned short u16x4 __attribute__((ext_vector_type(4)));

__device__ __forceinline__ float bf2f(unsigned int bits) {
    return __uint_as_float(bits << 16);
}
__device__ __forceinline__ unsigned short f2bf(float f) {
    unsigned int x = __float_as_uint(f);
    return (unsigned short)((x + 0x7fffu + ((x >> 16) & 1u)) >> 16);
}

#define GLD16(gp, lp) \
    __builtin_amdgcn_global_load_lds( \
        (const __attribute__((address_space(1))) unsigned int*)(gp), \
        (__attribute__((address_space(3))) unsigned int*)(lp), 16, 0, 0)

// ---------------------------------------------------------------- weight transpose+convert
__global__ __launch_bounds__(256)
void tr_k(const float* __restrict__ src, unsigned short* __restrict__ dst,
          int R, int C, size_t ss, size_t ds)
{
    __shared__ float tile[32][33];
    src += (size_t)blockIdx.z * ss;
    dst += (size_t)blockIdx.z * ds;
    const int r0 = blockIdx.y * 32, c0 = blockIdx.x * 32;
    const int tr = threadIdx.x >> 3, tc = (threadIdx.x & 7) * 4;
    f32x4 v = *(const f32x4*)(src + (size_t)(r0 + tr) * C + c0 + tc);
    tile[tr][tc + 0] = v[0]; tile[tr][tc + 1] = v[1];
    tile[tr][tc + 2] = v[2]; tile[tr][tc + 3] = v[3];
    __syncthreads();
    u16x4 o;
    o[0] = f2bf(tile[tc + 0][tr]); o[1] = f2bf(tile[tc + 1][tr]);
    o[2] = f2bf(tile[tc + 2][tr]); o[3] = f2bf(tile[tc + 3][tr]);
    *(u16x4*)(dst + (size_t)(c0 + tr) * R + r0 + tc) = o;
}

// ---------------------------------------------------------------- qkv bias concat
__global__ __launch_bounds__(256)
void biascat_k(const float* __restrict__ bq, const float* __restrict__ bk,
               const float* __restrict__ bv, float* __restrict__ bqkv)
{
    const int i = blockIdx.x * 256 + threadIdx.x;
    if (i >= L_NUM * QKVN) return;
    const int l = i / QKVN, n = i % QKVN;
    float v;
    if (n < 768)       v = bq[l * 768 + n];
    else if (n < 1536) v = bk[l * 768 + n - 768];
    else               v = bv[l * 768 + n - 1536];
    bqkv[i] = v;
}

// ---------------------------------------------------------------- embedding
__global__ __launch_bounds__(256)
void embed_k(const int* __restrict__ ids, const float* __restrict__ tok,
             const float* __restrict__ pos, float* __restrict__ xf,
             unsigned short* __restrict__ xb)
{
    const int row = blockIdx.x;
    const int s = row >> 5;
    const int id = ids[row];
    const size_t rb = (size_t)row * E_DIM;
    for (int e = threadIdx.x; e < E_DIM; e += 256) {
        float v = tok[(size_t)id * E_DIM + e] + pos[(size_t)s * E_DIM + e];
        xf[rb + e] = v;
        xb[rb + e] = f2bf(v);
    }
}

// ---------------------------------------------------------------- GEMM v3
// C[M,N] = A[M,K](bf16,row) @ BT[N,K](bf16,row)^T + bias
// 256x256x64 tile, 8 waves (2Mx4N, wave-tile 128x64), 2-deep LDS dbuf 128KiB.
// Counted vmcnt(8) pipeline with RAW s_barrier (no __syncthreads -> no
// compiler vmcnt(0) drain). LDS chunk-XOR swizzle (c8 ^= row&7), applied as
// inverse on the gload SOURCE (linear LDS dest) and on ds_read addr.
// MODE 0: bf16 out. MODE 1: bf16+relu. MODE 2: f32 C += v.
template<int MODE>
__global__ __launch_bounds__(512, 2)
void gemm3_k(const unsigned short* __restrict__ A, const unsigned short* __restrict__ BT,
             const float* __restrict__ bias, void* __restrict__ Cout,
             int lda, int ldb, int ldc, int K, int JT)
{
    __shared__ unsigned short As[2 * 256 * 64];   // 64 KB
    __shared__ unsigned short Bs[2 * 256 * 64];   // 64 KB
    const int t = threadIdx.x;
    const int d = blockIdx.x;
    const int qd = d >> 3, rd = d & 7;            // XCD swizzle: panel/XCD
    const int jb = qd % JT;
    const int ib = rd + 8 * (qd / JT);            // M/256=64 panels, bijective
    const int i0 = ib * 256, j0 = jb * 256;

    const int lane = t & 63, wave = t >> 6;
    const int wm = wave >> 2, wn = wave & 3;      // 2 x 4 wave grid
    const int lr = lane & 15, lg = lane >> 4;

    // staging: issue covers 64 rows; thread -> row t>>3, source chunk swizzled
    const int strow = t >> 3;
    const int stchk = (t & 7) ^ (strow & 7);      // inverse-swizzled src chunk
    const unsigned short* Ab = A  + (size_t)(i0 + strow) * lda + stchk * 8;
    const unsigned short* Bb = BT + (size_t)(j0 + strow) * ldb + stchk * 8;
    const int ldst = t * 8;                       // linear LDS dest (shorts)

    f32x4 acc[8][4];
    #pragma unroll
    for (int mf = 0; mf < 8; mf++)
        #pragma unroll
        for (int nf = 0; nf < 4; nf++) acc[mf][nf] = (f32x4)0.0f;

    // read-side swizzled k-chunk offset (shorts), ks=0; ks=1 is ^32
    const int rsw = (lg ^ (lr & 7)) * 8;
    const int NT = K >> 6;

#define STAGE3(k0, cbuf) do { \
    _Pragma("unroll") \
    for (int ii = 0; ii < 4; ii++) \
        GLD16(Ab + (size_t)(ii * 64) * lda + (k0), &As[(cbuf) * 16384 + ii * 4096 + ldst]); \
    _Pragma("unroll") \
    for (int ii = 0; ii < 4; ii++) \
        GLD16(Bb + (size_t)(ii * 64) * ldb + (k0), &Bs[(cbuf) * 16384 + ii * 4096 + ldst]); \
} while (0)

#define COMPUTE3(cbuf) do { \
    _Pragma("unroll") \
    for (int ks = 0; ks < 2; ks++) { \
        u32x4 a[8], b[4]; \
        _Pragma("unroll") \
        for (int mf = 0; mf < 8; mf++) \
            a[mf] = *(const u32x4*)(&As[(cbuf) * 16384 + (wm * 128 + mf * 16 + lr) * 64 + (rsw ^ (ks * 32))]); \
        _Pragma("unroll") \
        for (int nf = 0; nf < 4; nf++) \
            b[nf] = *(const u32x4*)(&Bs[(cbuf) * 16384 + (wn * 64 + nf * 16 + lr) * 64 + (rsw ^ (ks * 32))]); \
        __builtin_amdgcn_s_setprio(1); \
        _Pragma("unroll") \
        for (int mf = 0; mf < 8; mf++) \
            _Pragma("unroll") \
            for (int nf = 0; nf < 4; nf++) \
                asm volatile("v_mfma_f32_16x16x32_bf16 %0, %1, %2, %0" \
                             : "+v"(acc[mf][nf]) : "v"(a[mf]), "v"(b[nf])); \
        __builtin_amdgcn_s_setprio(0); \
    } \
} while (0)

    STAGE3(0, 0);
    STAGE3(64, 1);

    for (int kt = 0; kt < NT - 1; ++kt) {
        // in-order vmcnt: keep newest 8 (tile kt+1) in flight, tile kt done
        asm volatile("s_waitcnt vmcnt(8)" ::: "memory");
        __builtin_amdgcn_s_barrier();
        asm volatile("" ::: "memory");
        __builtin_amdgcn_sched_barrier(0);
        COMPUTE3(kt & 1);
        __builtin_amdgcn_sched_barrier(0);
        asm volatile("" ::: "memory");
        __builtin_amdgcn_s_barrier();          // all waves done reading buf[kt&1]
        asm volatile("" ::: "memory");
        if (kt + 2 < NT) STAGE3((kt + 2) * 64, kt & 1);
        __builtin_amdgcn_sched_barrier(0);
    }
    asm volatile("s_waitcnt vmcnt(0)" ::: "memory");
    __builtin_amdgcn_s_barrier();
    asm volatile("" ::: "memory");
    __builtin_amdgcn_sched_barrier(0);
    COMPUTE3((NT - 1) & 1);

    asm volatile("s_nop 7\n\ts_nop 7");   // MFMA D-read hazard insurance
    #pragma unroll
    for (int nf = 0; nf < 4; nf++) {
        const int col = j0 + wn * 64 + nf * 16 + lr;
        const float bv = bias ? bias[col] : 0.0f;
        #pragma unroll
        for (int mf = 0; mf < 8; mf++) {
            #pragma unroll
            for (int jj = 0; jj < 4; jj++) {
                const int row = i0 + wm * 128 + mf * 16 + lg * 4 + jj;
                const size_t idx = (size_t)row * ldc + col;
                float v = acc[mf][nf][jj] + bv;
                if (MODE == 1) v = fmaxf(v, 0.0f);
                if (MODE == 2) ((float*)Cout)[idx] += v;
                else           ((unsigned short*)Cout)[idx] = f2bf(v);
            }
        }
    }
#undef STAGE3
#undef COMPUTE3
}

// ---------------------------------------------------------------- attention (proven round 6)
__global__ __launch_bounds__(768)
void attn_k(unsigned short* __restrict__ qkv)
{
    __shared__ float attn_t[32 * 36];   // [c][q]
    const int s = blockIdx.x;
    const int t = threadIdx.x;
    const int base = s * 32;

    if (t < 64) {
        const int lr = t & 15, lg = t >> 4;
        f32x4 sacc[2][2];
        #pragma unroll
        for (int m = 0; m < 2; m++)
            #pragma unroll
            for (int n = 0; n < 2; n++) sacc[m][n] = (f32x4)0.0f;
        const unsigned short* Qb = qkv + (size_t)base * QKVN;
        #pragma unroll 4
        for (int k0 = 0; k0 < E_DIM; k0 += 32) {
            u32x4 a0 = *(const u32x4*)(Qb + (size_t)lr        * QKVN + k0 + lg * 8);
            u32x4 a1 = *(const u32x4*)(Qb + (size_t)(16 + lr) * QKVN + k0 + lg * 8);
            u32x4 b0 = *(const u32x4*)(Qb + (size_t)lr        * QKVN + 768 + k0 + lg * 8);
            u32x4 b1 = *(const u32x4*)(Qb + (size_t)(16 + lr) * QKVN + 768 + k0 + lg * 8);
            asm volatile("v_mfma_f32_16x16x32_bf16 %0, %1, %2, %0" : "+v"(sacc[0][0]) : "v"(a0), "v"(b0));
            asm volatile("v_mfma_f32_16x16x32_bf16 %0, %1, %2, %0" : "+v"(sacc[0][1]) : "v"(a0), "v"(b1));
            asm volatile("v_mfma_f32_16x16x32_bf16 %0, %1, %2, %0" : "+v"(sacc[1][0]) : "v"(a1), "v"(b0));
            asm volatile("v_mfma_f32_16x16x32_bf16 %0, %1, %2, %0" : "+v"(sacc[1][1]) : "v"(a1), "v"(b1));
        }
        asm volatile("s_nop 7\n\ts_nop 7");
        const float scale = 0.036084391824351615f;
        float p[2][2][4];
        #pragma unroll
        for (int m = 0; m < 2; m++) {
            #pragma unroll
            for (int j = 0; j < 4; j++) {
                float v0 = sacc[m][0][j] * scale;
                float v1 = sacc[m][1][j] * scale;
                float mx = fmaxf(v0, v1);
                #pragma unroll
                for (int o = 1; o < 16; o <<= 1) mx = fmaxf(mx, __shfl_xor(mx, o));
                float e0 = expf(v0 - mx), e1 = expf(v1 - mx);
                float sm = e0 + e1;
                #pragma unroll
                for (int o = 1; o < 16; o <<= 1) sm += __shfl_xor(sm, o);
                const float r = 1.0f / sm;
                p[m][0][j] = e0 * r;
                p[m][1][j] = e1 * r;
            }
        }
        #pragma unroll
        for (int m = 0; m < 2; m++)
            #pragma unroll
            for (int n = 0; n < 2; n++)
                #pragma unroll
                for (int j = 0; j < 4; j++)
                    attn_t[(n * 16 + lr) * 36 + m * 16 + lg * 4 + j] = p[m][n][j];
    }
    __syncthreads();
    if (t < E_DIM) {
        float o[32];
        #pragma unroll
        for (int q = 0; q < 32; q++) o[q] = 0.f;
        for (int c = 0; c < 32; c++) {
            const float vv = bf2f(qkv[(size_t)(base + c) * QKVN + 1536 + t]);
            const f32x4* arow = (const f32x4*)(&attn_t[c * 36]);
            #pragma unroll
            for (int q8 = 0; q8 < 8; q8++) {
                f32x4 a4 = arow[q8];
                o[q8 * 4 + 0] += a4[0] * vv;
                o[q8 * 4 + 1] += a4[1] * vv;
                o[q8 * 4 + 2] += a4[2] * vv;
                o[q8 * 4 + 3] += a4[3] * vv;
            }
        }
        #pragma unroll
        for (int q = 0; q < 32; q++)
            qkv[(size_t)(base + q) * QKVN + t] = f2bf(o[q]);   // ao over Q
    }
}

// ---------------------------------------------------------------- layernorm (in-place on xf)
__global__ __launch_bounds__(256)
void ln_k(float* x, const float* __restrict__ g, const float* __restrict__ bta,
          unsigned short* __restrict__ xbo)
{
    __shared__ float red[8];
    const int row = blockIdx.x, t = threadIdx.x;
    const size_t rb = (size_t)row * E_DIM;
    float v[3];
    float s = 0.f, s2 = 0.f;
    #pragma unroll
    for (int i = 0; i < 3; i++) {
        const float a = x[rb + t + i * 256];
        v[i] = a; s += a; s2 += a * a;
    }
    #pragma unroll
    for (int o = 32; o > 0; o >>= 1) { s += __shfl_down(s, o); s2 += __shfl_down(s2, o); }
    const int wv_ = t >> 6;
    if ((t & 63) == 0) { red[wv_] = s; red[4 + wv_] = s2; }
    __syncthreads();
    if (t == 0) {
        red[0] = red[0] + red[1] + red[2] + red[3];
        red[4] = red[4] + red[5] + red[6] + red[7];
    }
    __syncthreads();
    const float mu   = red[0] * (1.f / E_DIM);
    const float var  = red[4] * (1.f / E_DIM) - mu * mu;
    const float rinv = rsqrtf(var + 1e-5f);
    #pragma unroll
    for (int i = 0; i < 3; i++) {
        const int e = t + i * 256;
        const float y = (v[i] - mu) * rinv * g[e] + bta[e];
        x[rb + e] = y;
        xbo[rb + e] = f2bf(y);
    }
}

// ---------------------------------------------------------------- classifier
__global__ __launch_bounds__(256)
void cls_k(const float* __restrict__ xf, const float* __restrict__ Wc,
           const float* __restrict__ bc, float* __restrict__ out)
{
    __shared__ float red[256];
    const int t = threadIdx.x;
    const int o = t >> 2, p = t & 3;
    const int b = o >> 1, c = o & 1;
    float acc = 0.f;
    for (int e = p; e < E_DIM; e += 4)
        acc += xf[(size_t)b * E_DIM + e] * Wc[e * 2 + c];
    red[t] = acc;
    __syncthreads();
    if (p == 0) out[o] = red[t] + red[t + 1] + red[t + 2] + red[t + 3] + bc[c];
}

// ---------------------------------------------------------------- launch
extern "C" void kernel_launch(void* const* d_in, const int* in_sizes, int n_in,
                              void* d_out, int out_size, void* d_ws, size_t ws_size,
                              hipStream_t stream)
{
    (void)in_sizes; (void)n_in; (void)out_size;
    const int*   ids = (const int*)  d_in[0];
    const float* tok = (const float*)d_in[1];
    const float* pos = (const float*)d_in[2];
    const float* Wq  = (const float*)d_in[3];
    const float* bq  = (const float*)d_in[4];
    const float* Wk  = (const float*)d_in[5];
    const float* bk  = (const float*)d_in[6];
    const float* Wv  = (const float*)d_in[7];
    const float* bv  = (const float*)d_in[8];
    const float* Wo  = (const float*)d_in[9];
    const float* bo  = (const float*)d_in[10];
    const float* g1  = (const float*)d_in[11];
    const float* be1 = (const float*)d_in[12];
    const float* g2  = (const float*)d_in[13];
    const float* be2 = (const float*)d_in[14];
    const float* W1  = (const float*)d_in[15];
    const float* bf1 = (const float*)d_in[16];
    const float* W2  = (const float*)d_in[17];
    const float* bf2 = (const float*)d_in[18];
    const float* Wc  = (const float*)d_in[19];
    const float* bc  = (const float*)d_in[20];
    float* out = (float*)d_out;

    auto al = [](size_t b) { return (b + 255) & ~(size_t)255; };
    const size_t NE = (size_t)NTOK * E_DIM;
    const size_t sEE = (size_t)E_DIM * E_DIM, sEF = (size_t)E_DIM * F_DIM;
    const size_t fixed = al(NE * 4) + al(NE * 2)
                       + al((size_t)L_NUM * QKVN * E_DIM * 2) + al((size_t)L_NUM * sEE * 2)
                       + al((size_t)L_NUM * sEF * 2) + al((size_t)L_NUM * sEF * 2)
                       + al((size_t)L_NUM * QKVN * 4);
    const bool big = ws_size >= fixed + al((size_t)NTOK * F_DIM * 2);

    char* p = (char*)d_ws;
    auto carve = [&](size_t bytes) { char* r = p; p += (bytes + 255) & ~(size_t)255; return r; };
    float*          xf    = (float*)carve(NE * 4);
    unsigned short* xb    = (unsigned short*)carve(NE * 2);
    unsigned short* qkv   = (unsigned short*)carve(big ? (size_t)NTOK * F_DIM * 2
                                                       : (size_t)NTOK * QKVN * 2);
    unsigned short* wqkvT = (unsigned short*)carve((size_t)L_NUM * QKVN * E_DIM * 2);
    unsigned short* woT   = (unsigned short*)carve((size_t)L_NUM * sEE * 2);
    unsigned short* w1T   = (unsigned short*)carve((size_t)L_NUM * sEF * 2);
    unsigned short* w2T   = (unsigned short*)carve((size_t)L_NUM * sEF * 2);
    float*          bqkv  = (float*)carve((size_t)L_NUM * QKVN * 4);
    unsigned short* h1c   = qkv;   // overlays qkv (dead after Wo-GEMM)

    tr_k<<<dim3(24, 24, 4), 256, 0, stream>>>(Wq, wqkvT,              768, 768, sEE, (size_t)QKVN * E_DIM);
    tr_k<<<dim3(24, 24, 4), 256, 0, stream>>>(Wk, wqkvT + 768 * 768,  768, 768, sEE, (size_t)QKVN * E_DIM);
    tr_k<<<dim3(24, 24, 4), 256, 0, stream>>>(Wv, wqkvT + 1536 * 768, 768, 768, sEE, (size_t)QKVN * E_DIM);
    tr_k<<<dim3(24, 24, 4), 256, 0, stream>>>(Wo, woT, 768, 768, sEE, sEE);
    tr_k<<<dim3(96, 24, 4), 256, 0, stream>>>(W1, w1T, 768, 3072, sEF, sEF);
    tr_k<<<dim3(24, 96, 4), 256, 0, stream>>>(W2, w2T, 3072, 768, sEF, sEF);
    biascat_k<<<(L_NUM * QKVN + 255) / 256, 256, 0, stream>>>(bq, bk, bv, bqkv);

    embed_k<<<NTOK, 256, 0, stream>>>(ids, tok, pos, xf, xb);

    for (int l = 0; l < L_NUM; l++) {
        const unsigned short* wqkv_l = wqkvT + (size_t)l * QKVN * E_DIM;
        const unsigned short* wo_l   = woT + (size_t)l * sEE;
        const unsigned short* w1_l   = w1T + (size_t)l * sEF;
        const unsigned short* w2_l   = w2T + (size_t)l * sEF;

        // qkv = x @ [Wq|Wk|Wv] + b   (N=2304, JT=9)
        gemm3_k<0><<<64 * 9, 512, 0, stream>>>(xb, wqkv_l, bqkv + l * QKVN, qkv,
                                               E_DIM, E_DIM, QKVN, E_DIM, 9);
        attn_k<<<S_LEN, 768, 0, stream>>>(qkv);
        // xf += ao @ Wo + bo   (N=768, JT=3)
        gemm3_k<2><<<64 * 3, 512, 0, stream>>>(qkv, wo_l, bo + l * E_DIM, xf,
                                               QKVN, E_DIM, E_DIM, E_DIM, 3);
        ln_k<<<NTOK, 256, 0, stream>>>(xf, g1 + l * E_DIM, be1 + l * E_DIM, xb);
        if (big) {
            gemm3_k<1><<<64 * 12, 512, 0, stream>>>(xb, w1_l, bf1 + (size_t)l * F_DIM, h1c,
                                                    E_DIM, E_DIM, F_DIM, E_DIM, 12);
            gemm3_k<2><<<64 * 3, 512, 0, stream>>>(h1c, w2_l, bf2 + l * E_DIM, xf,
                                                   F_DIM, F_DIM, E_DIM, F_DIM, 3);
        } else {
            for (int c = 0; c < 2; c++) {
                const int c0 = c * 1536;
                gemm3_k<1><<<64 * 6, 512, 0, stream>>>(xb, w1_l + (size_t)c0 * E_DIM,
                                                       bf1 + (size_t)l * F_DIM + c0, h1c,
                                                       E_DIM, E_DIM, 1536, E_DIM, 6);
                gemm3_k<2><<<64 * 3, 512, 0, stream>>>(h1c, w2_l + c0,
                                                       c == 0 ? (bf2 + l * E_DIM) : (const float*)nullptr,
                                                       xf, 1536, F_DIM, E_DIM, 1536, 3);
            }
        }
        ln_k<<<NTOK, 256, 0, stream>>>(xf, g2 + l * E_DIM, be2 + l * E_DIM, xb);
    }

    cls_k<<<1, 256, 0, stream>>>(xf, Wc, bc, out);
}